// Round 7
// baseline (459.901 us; speedup 1.0000x reference)
//
#include <hip/hip_runtime.h>

namespace {

constexpr int T_STEPS = 1000;
constexpr int NB      = 4096;
constexpr float LOG2E = 1.4426950408889634f;

typedef float v2f __attribute__((ext_vector_type(2)));

__device__ __forceinline__ float fexp2(float x) { return __builtin_amdgcn_exp2f(x); }
__device__ __forceinline__ float frcp(float x)  { return __builtin_amdgcn_rcpf(x); }
__device__ __forceinline__ v2f mkv2(float a, float b) { v2f r; r.x = a; r.y = b; return r; }

__device__ __forceinline__ v2f pkfma(v2f a, v2f b, v2f c) {
#if __has_builtin(__builtin_elementwise_fma)
    return __builtin_elementwise_fma(a, b, c);   // v_pk_fma_f32
#else
    v2f r; r.x = fmaf(a.x, b.x, c.x); r.y = fmaf(a.y, b.y, c.y); return r;
#endif
}

// DPP on the VALU pipe (R3/R5-proven patterns).
template<int CTRL>
__device__ __forceinline__ float dppf(float v) {
    int i = __float_as_int(v);
    return __int_as_float(__builtin_amdgcn_update_dpp(i, i, CTRL, 0xF, 0xF, false));
}

// v_permlane32_swap (gfx950, VALU; R5-HW-proven): lanes<32 keep a, lanes>=32
// receive lower half's b.
__device__ __forceinline__ float xlow(float a, float b) {
    auto r = __builtin_amdgcn_permlane32_swap(__float_as_int(a), __float_as_int(b),
                                              false, false);
    return __int_as_float(r[0]);
}

// Layer-pipelined LSTM (R5 structure) + pk_fma matvecs + 4-step prefetch ring
// (R6). One element = 32 lanes across the two wave halves: lanes 0-31 layer 0
// at body i, lanes 32-63 layer 1 at body i-1, same instruction stream; handoff
// via permlane32_swap. 2048 waves = 2 waves/SIMD -> HW fills chain stalls.
// Within each 16-lane group: R3-proven row scheme (u=q&7, hlf=q>>3, rows
// r0=hlf*16+u, r1=r0+8), DPP-only cross-lane, probe-verified rotation layout.
__global__ __launch_bounds__(256, 2)
void lstm_fused_kernel(
    const float* __restrict__ state, const float* __restrict__ dist,
    const float* __restrict__ e1W1, const float* __restrict__ e1b1,
    const float* __restrict__ e1W2, const float* __restrict__ e1b2,
    const float* __restrict__ e2W1, const float* __restrict__ e2b1,
    const float* __restrict__ e2W2, const float* __restrict__ e2b2,
    const float* __restrict__ Wih0, const float* __restrict__ Whh0,
    const float* __restrict__ bih0, const float* __restrict__ bhh0,
    const float* __restrict__ Wih1, const float* __restrict__ Whh1,
    const float* __restrict__ bih1, const float* __restrict__ bhh1,
    const float* __restrict__ decW, const float* __restrict__ decb,
    const float* __restrict__ finW, const float* __restrict__ finb,
    const float* __restrict__ fin2W, const float* __restrict__ fin2b,
    float* __restrict__ out)
{
    const int tid = (int)threadIdx.x;
    const int q   = tid & 15;                  // lane in 16-group
    const int lay = (tid >> 5) & 1;            // wave half: 0=layer0, 1=layer1
    const int n   = blockIdx.x * 8 + (tid >> 6) * 2 + ((tid >> 4) & 1);
    const int u   = q & 7;
    const int hlf = q >> 3;
    const int r0  = hlf * 16 + u;              // row A (i_u | g_u)
    const int r1  = r0 + 8;                    // row B (f_u | o_u)

    // probe row_ror direction once: slot k holds h[(u+sgn*k)&7]
    const int pv  = __builtin_amdgcn_update_dpp(0, q, 0x121, 0xF, 0xF, true);
    const int sgn = (pv == ((q + 1) & 15)) ? 1 : -1;
    auto pidx = [&](int k) { return (u + sgn * k) & 7; };

    const float sA   = hlf ? (-2.0f * LOG2E) : (-LOG2E);   // row A: sigmoid | tanh
    const float sB   = -LOG2E;                              // row B always sigmoid
    const float mulA = hlf ? 2.0f : 1.0f;
    const float addA = hlf ? -1.0f : 0.0f;

    // ---- this half's layer weights, packed v2f (x-cols natural for layer0,
    //      slot-permuted for layer1; h-cols slot-permuted) ----
    const float* Wih = lay ? Wih1 : Wih0;
    const float* Whh = lay ? Whh1 : Whh0;
    const float* bih = lay ? bih1 : bih0;
    const float* bhh = lay ? bhh1 : bhh0;
    v2f wxa[4], wha[4], wxb[4], whb[4];
#pragma unroll
    for (int k = 0; k < 4; ++k) {
        const int k0 = 2 * k, k1 = 2 * k + 1;
        const int p0 = pidx(k0), p1 = pidx(k1);
        const int x0c = lay ? p0 : k0, x1c = lay ? p1 : k1;
        wxa[k] = mkv2(Wih[r0 * 8 + x0c] * sA, Wih[r0 * 8 + x1c] * sA);
        wha[k] = mkv2(Whh[r0 * 8 + p0] * sA, Whh[r0 * 8 + p1] * sA);
        wxb[k] = mkv2(Wih[r1 * 8 + x0c] * sB, Wih[r1 * 8 + x1c] * sB);
        whb[k] = mkv2(Whh[r1 * 8 + p0] * sB, Whh[r1 * 8 + p1] * sB);
    }
    const float bA = (bih[r0] + bhh[r0]) * sA;
    const float bB = (bih[r1] + bhh[r1]) * sB;

    // decoder (meaningful on upper half; all lanes run in lockstep)
    const int dr = q & 3;
    v2f dwr2[4];
#pragma unroll
    for (int k = 0; k < 4; ++k)
        dwr2[k] = mkv2(decW[dr * 8 + pidx(2 * k)], decW[dr * 8 + pidx(2 * k + 1)]);
    const float db = decb[dr];
    float fwp[4]; float fb;
    {
        const float* Wp = (u < 4) ? finW : fin2W;
        const float* bp = (u < 4) ? finb : fin2b;
        const int oo = u & 3;
#pragma unroll
        for (int jj = 0; jj < 4; ++jj) fwp[jj] = Wp[oo * 4 + ((dr + jj) & 3)];
        fb = bp[oo];
    }

    // ---------------- encoders: this half's layer h/c init (R5-verbatim) ----
    float c;
    v2f hr0, hr1, hr2, hr3;
    {
        float s[16];
#pragma unroll
        for (int k = 0; k < 16; ++k) s[k] = state[n * 16 + k];
        float hm1[4], hm2[4];
#pragma unroll
        for (int m = 0; m < 4; ++m) {
            float a = e1b1[m], b = e2b1[m];
#pragma unroll
            for (int k = 0; k < 16; ++k) {
                a = fmaf(s[k], e1W1[m * 16 + k], a);
                b = fmaf(s[k], e2W1[m * 16 + k], b);
            }
            hm1[m] = fmaxf(a, 0.0f); hm2[m] = fmaxf(b, 0.0f);
        }
        const int off = lay * 8;
        float hs[8];
#pragma unroll
        for (int k = 0; k < 8; ++k) {
            const int p = pidx(k);
            float a = e1b2[off + p];
#pragma unroll
            for (int m = 0; m < 4; ++m) a = fmaf(hm1[m], e1W2[(off + p) * 4 + m], a);
            hs[k] = fmaxf(a, 0.0f);            // own layer h init, slot layout
        }
        hr0 = mkv2(hs[0], hs[1]); hr1 = mkv2(hs[2], hs[3]);
        hr2 = mkv2(hs[4], hs[5]); hr3 = mkv2(hs[6], hs[7]);
        float cc = e2b2[off + u];
#pragma unroll
        for (int m = 0; m < 4; ++m) cc = fmaf(hm2[m], e2W2[(off + u) * 4 + m], cc);
        c = fmaxf(cc, 0.0f);                   // own layer c init
    }

    // ---------------- x stream + output pointer ----------------
    const float4* dp = reinterpret_cast<const float4*>(dist) + (size_t)n * 2;
    constexpr size_t TS4 = (size_t)NB * 2;
    float* outp = out + ((u < 4) ? ((size_t)n * 4 + u)
                                 : ((size_t)T_STEPS * NB * 4 + (size_t)n * 4 + (u - 4)));
    const bool doStore = (lay == 1) && (q < 8);

    // one body = one layer pass + decoder. maskUp: body 0 keeps upper state.
    auto body = [&](const float4& lo, const float4& hi, float* op,
                    bool maskUp, bool doSt) {
        // lower lanes keep their loaded x; upper lanes receive lower's h0 slots
        const float xi0 = xlow(lo.x, hr0.x), xi1 = xlow(lo.y, hr0.y);
        const float xi2 = xlow(lo.z, hr1.x), xi3 = xlow(lo.w, hr1.y);
        const float xi4 = xlow(hi.x, hr2.x), xi5 = xlow(hi.y, hr2.y);
        const float xi6 = xlow(hi.z, hr3.x), xi7 = xlow(hi.w, hr3.y);
        const v2f X0 = mkv2(xi0, xi1), X1 = mkv2(xi2, xi3);
        const v2f X2 = mkv2(xi4, xi5), X3 = mkv2(xi6, xi7);
        // row A / row B matvecs, two independent pk chains each
        v2f pa = pkfma(X0, wxa[0], mkv2(bA, 0.0f));
        pa = pkfma(X1, wxa[1], pa);
        pa = pkfma(hr0, wha[0], pa);
        pa = pkfma(hr1, wha[1], pa);
        v2f qa = pkfma(X2, wxa[2], mkv2(0.0f, 0.0f));
        qa = pkfma(X3, wxa[3], qa);
        qa = pkfma(hr2, wha[2], qa);
        qa = pkfma(hr3, wha[3], qa);
        v2f sa = pa + qa;
        const float A = sa.x + sa.y;
        v2f pb = pkfma(X0, wxb[0], mkv2(bB, 0.0f));
        pb = pkfma(X1, wxb[1], pb);
        pb = pkfma(hr0, whb[0], pb);
        pb = pkfma(hr1, whb[1], pb);
        v2f qb = pkfma(X2, wxb[2], mkv2(0.0f, 0.0f));
        qb = pkfma(X3, wxb[3], qb);
        qb = pkfma(hr2, whb[2], qb);
        qb = pkfma(hr3, whb[3], qb);
        v2f sb = pb + qb;
        const float B = sb.x + sb.y;
        float a0 = fmaf(frcp(1.0f + fexp2(A)), mulA, addA);  // sig(i)|tanh(g)
        float a1 = frcp(1.0f + fexp2(B));                     // sig(f)|sig(o)
        const float s0 = dppf<0x128>(a0);    // xor-8 partner
        const float s1 = dppf<0x128>(a1);
        const float prod = a0 * s0;          // sig(i)*tanh(g) on both halves
        const float fg = hlf ? s1 : a1;
        const float og = hlf ? a1 : s1;
        float cn = fmaf(fg, c, prod);
        const float th = fmaf(frcp(1.0f + fexp2(cn * (-2.0f * LOG2E))), 2.0f, -1.0f);
        float hn = og * th;
        if (maskUp) {                        // body 0: upper half keeps init state
            cn = lay ? c      : cn;
            hn = lay ? hr0.x  : hn;          // slot 0 = own-unit h
        }
        c = cn;
        {
            const float t1 = dppf<0x121>(hn), t2 = dppf<0x122>(hn), t3 = dppf<0x123>(hn);
            const float t4 = dppf<0x124>(hn), t5 = dppf<0x125>(hn), t6 = dppf<0x126>(hn);
            const float t7 = dppf<0x127>(hn);
            hr0 = mkv2(hn, t1); hr1 = mkv2(t2, t3);
            hr2 = mkv2(t4, t5); hr3 = mkv2(t6, t7);
        }
        // decoder + heads on the fresh h (upper half = h1 of step i-1)
        v2f dd = pkfma(hr0, dwr2[0], mkv2(db, 0.0f));
        dd = pkfma(hr1, dwr2[1], dd);
        v2f de = pkfma(hr2, dwr2[2], mkv2(0.0f, 0.0f));
        de = pkfma(hr3, dwr2[3], de);
        v2f ds = dd + de;
        float da = fmaxf(ds.x + ds.y, 0.0f);
        const float d1 = dppf<0x39>(da);
        const float d2 = dppf<0x4E>(da);
        const float d3 = dppf<0x93>(da);
        float o = fb;
        o = fmaf(da, fwp[0], o); o = fmaf(d1, fwp[1], o);
        o = fmaf(d2, fwp[2], o); o = fmaf(d3, fwp[3], o);
        if (doSt && doStore) *op = o;
    };

    // ---- 4-step register prefetch ring ----
    float4 g0a = dp[0],       g0b = dp[1];
    float4 g1a = dp[TS4],     g1b = dp[TS4 + 1];
    float4 g2a = dp[2 * TS4], g2b = dp[2 * TS4 + 1];
    float4 g3a = dp[3 * TS4], g3b = dp[3 * TS4 + 1];
    const float4* pf = dp + 4 * TS4;           // next load: t = 4

    // body 0: lower does step 0; upper idles (masked), no store
    {
        float4 na = pf[0], nb = pf[1]; pf += TS4;
        body(g0a, g0b, nullptr, true, false);
        g0a = na; g0b = nb;
    }
    // bodies 1..3
    {
        float4 na = pf[0], nb = pf[1]; pf += TS4;
        body(g1a, g1b, outp, false, true); outp += (size_t)NB * 4;
        g1a = na; g1b = nb;
        na = pf[0]; nb = pf[1]; pf += TS4;
        body(g2a, g2b, outp, false, true); outp += (size_t)NB * 4;
        g2a = na; g2b = nb;
        na = pf[0]; nb = pf[1]; pf += TS4;
        body(g3a, g3b, outp, false, true); outp += (size_t)NB * 4;
        g3a = na; g3b = nb;
    }
    // main: bodies 4..995 (248 iters x 4), loading x8..x999
    for (int it = 0; it < 248; ++it) {
        float4 na, nb;
        na = pf[0]; nb = pf[1]; pf += TS4;
        body(g0a, g0b, outp, false, true); outp += (size_t)NB * 4;
        g0a = na; g0b = nb;
        na = pf[0]; nb = pf[1]; pf += TS4;
        body(g1a, g1b, outp, false, true); outp += (size_t)NB * 4;
        g1a = na; g1b = nb;
        na = pf[0]; nb = pf[1]; pf += TS4;
        body(g2a, g2b, outp, false, true); outp += (size_t)NB * 4;
        g2a = na; g2b = nb;
        na = pf[0]; nb = pf[1]; pf += TS4;
        body(g3a, g3b, outp, false, true); outp += (size_t)NB * 4;
        g3a = na; g3b = nb;
    }
    // tail: bodies 996..999 (no loads)
    body(g0a, g0b, outp, false, true); outp += (size_t)NB * 4;
    body(g1a, g1b, outp, false, true); outp += (size_t)NB * 4;
    body(g2a, g2b, outp, false, true); outp += (size_t)NB * 4;
    body(g3a, g3b, outp, false, true); outp += (size_t)NB * 4;
    // drain: upper processes h0(999) -> stores step 999 (lower result dead)
    body(g3a, g3b, outp, false, true);
}

} // namespace

extern "C" void kernel_launch(void* const* d_in, const int* in_sizes, int n_in,
                              void* d_out, int out_size, void* d_ws, size_t ws_size,
                              hipStream_t stream) {
    const float* state = (const float*)d_in[0];
    const float* dist  = (const float*)d_in[1];
    const float* e1W1  = (const float*)d_in[2];
    const float* e1b1  = (const float*)d_in[3];
    const float* e1W2  = (const float*)d_in[4];
    const float* e1b2  = (const float*)d_in[5];
    const float* e2W1  = (const float*)d_in[6];
    const float* e2b1  = (const float*)d_in[7];
    const float* e2W2  = (const float*)d_in[8];
    const float* e2b2  = (const float*)d_in[9];
    const float* Wih0  = (const float*)d_in[10];
    const float* Whh0  = (const float*)d_in[11];
    const float* bih0  = (const float*)d_in[12];
    const float* bhh0  = (const float*)d_in[13];
    const float* Wih1  = (const float*)d_in[14];
    const float* Whh1  = (const float*)d_in[15];
    const float* bih1  = (const float*)d_in[16];
    const float* bhh1  = (const float*)d_in[17];
    const float* decW  = (const float*)d_in[18];
    const float* decb  = (const float*)d_in[19];
    const float* finW  = (const float*)d_in[20];
    const float* finb  = (const float*)d_in[21];
    const float* fin2W = (const float*)d_in[22];
    const float* fin2b = (const float*)d_in[23];
    float* outp = (float*)d_out;

    lstm_fused_kernel<<<dim3(NB / 8), dim3(256), 0, stream>>>(
        state, dist,
        e1W1, e1b1, e1W2, e1b2,
        e2W1, e2b1, e2W2, e2b2,
        Wih0, Whh0, bih0, bhh0,
        Wih1, Whh1, bih1, bhh1,
        decW, decb, finW, finb, fin2W, fin2b,
        outp);
}

// Round 8
// 307.817 us; speedup vs baseline: 1.4941x; 1.4941x over previous
//
#include <hip/hip_runtime.h>

namespace {

constexpr int T_STEPS = 1000;
constexpr int NB      = 4096;
constexpr float LOG2E = 1.4426950408889634f;

typedef float v2f __attribute__((ext_vector_type(2)));

__device__ __forceinline__ float fexp2(float x) { return __builtin_amdgcn_exp2f(x); }
__device__ __forceinline__ float frcp(float x)  { return __builtin_amdgcn_rcpf(x); }
__device__ __forceinline__ v2f mkv2(float a, float b) { v2f r; r.x = a; r.y = b; return r; }

__device__ __forceinline__ v2f pkfma(v2f a, v2f b, v2f c) {
#if __has_builtin(__builtin_elementwise_fma)
    return __builtin_elementwise_fma(a, b, c);   // v_pk_fma_f32
#else
    v2f r; r.x = fmaf(a.x, b.x, c.x); r.y = fmaf(a.y, b.y, c.y); return r;
#endif
}

// DPP on the VALU pipe (R3/R6-HW-proven patterns).
template<int CTRL>
__device__ __forceinline__ float dppf(float v) {
    int i = __float_as_int(v);
    return __int_as_float(__builtin_amdgcn_update_dpp(i, i, CTRL, 0xF, 0xF, false));
}

// W=16 (R6 mapping, 1 wave/SIMD) + IN-LANE layer pipelining: per iteration,
// L0(t) and L1(t-1) are two INDEPENDENT dependency chains (L1 consumes the
// h0 generation kept from the previous iteration) -> the scheduler
// interleaves their serial activation chains; step chain ~halves. No
// cross-lane handoff, same instruction count as R6 (+16 VGPR of state).
__global__ __launch_bounds__(256, 1)
void lstm_fused_kernel(
    const float* __restrict__ state, const float* __restrict__ dist,
    const float* __restrict__ e1W1, const float* __restrict__ e1b1,
    const float* __restrict__ e1W2, const float* __restrict__ e1b2,
    const float* __restrict__ e2W1, const float* __restrict__ e2b1,
    const float* __restrict__ e2W2, const float* __restrict__ e2b2,
    const float* __restrict__ Wih0, const float* __restrict__ Whh0,
    const float* __restrict__ bih0, const float* __restrict__ bhh0,
    const float* __restrict__ Wih1, const float* __restrict__ Whh1,
    const float* __restrict__ bih1, const float* __restrict__ bhh1,
    const float* __restrict__ decW, const float* __restrict__ decb,
    const float* __restrict__ finW, const float* __restrict__ finb,
    const float* __restrict__ fin2W, const float* __restrict__ fin2b,
    float* __restrict__ out)
{
    const int tid = (int)threadIdx.x;
    const int q   = tid & 15;
    const int n   = blockIdx.x * 16 + (tid >> 4);
    const int u   = q & 7;
    const int hlf = q >> 3;
    const int r0  = hlf * 16 + u;   // row A (i_u | g_u)
    const int r1  = r0 + 8;         // row B (f_u | o_u)

    // probe row_ror direction once: slot k holds h[(u+sgn*k)&7]
    const int pv  = __builtin_amdgcn_update_dpp(0, q, 0x121, 0xF, 0xF, true);
    const int sgn = (pv == ((q + 1) & 15)) ? 1 : -1;
    auto pidx = [&](int k) { return (u + sgn * k) & 7; };

    const float sA   = hlf ? (-2.0f * LOG2E) : (-LOG2E);   // row A: sigmoid | tanh
    const float sB   = -LOG2E;                              // row B always sigmoid
    const float mulA = hlf ? 2.0f : 1.0f;
    const float addA = hlf ? -1.0f : 0.0f;

    // ---- packed weight rows (R6-verbatim; h-side in rotated slot layout) ----
    v2f wx0a[4], wh0a[4], wx0b[4], wh0b[4];
    v2f wx1a[4], wh1a[4], wx1b[4], wh1b[4];
#pragma unroll
    for (int k = 0; k < 4; ++k) {
        const int k0 = 2 * k, k1 = 2 * k + 1;
        const int p0 = pidx(k0), p1 = pidx(k1);
        wx0a[k] = mkv2(Wih0[r0 * 8 + k0] * sA, Wih0[r0 * 8 + k1] * sA);
        wh0a[k] = mkv2(Whh0[r0 * 8 + p0] * sA, Whh0[r0 * 8 + p1] * sA);
        wx0b[k] = mkv2(Wih0[r1 * 8 + k0] * sB, Wih0[r1 * 8 + k1] * sB);
        wh0b[k] = mkv2(Whh0[r1 * 8 + p0] * sB, Whh0[r1 * 8 + p1] * sB);
        wx1a[k] = mkv2(Wih1[r0 * 8 + p0] * sA, Wih1[r0 * 8 + p1] * sA);
        wh1a[k] = mkv2(Whh1[r0 * 8 + p0] * sA, Whh1[r0 * 8 + p1] * sA);
        wx1b[k] = mkv2(Wih1[r1 * 8 + p0] * sB, Wih1[r1 * 8 + p1] * sB);
        wh1b[k] = mkv2(Whh1[r1 * 8 + p0] * sB, Whh1[r1 * 8 + p1] * sB);
    }
    const float bA0 = (bih0[r0] + bhh0[r0]) * sA, bB0 = (bih0[r1] + bhh0[r1]) * sB;
    const float bA1 = (bih1[r0] + bhh1[r0]) * sA, bB1 = (bih1[r1] + bhh1[r1]) * sB;

    // decoder (R6-verbatim)
    const int dr = q & 3;
    v2f dwr2[4];
#pragma unroll
    for (int k = 0; k < 4; ++k)
        dwr2[k] = mkv2(decW[dr * 8 + pidx(2 * k)], decW[dr * 8 + pidx(2 * k + 1)]);
    const float db = decb[dr];
    float fwp[4]; float fb;
    {
        const float* Wp = (u < 4) ? finW : fin2W;
        const float* bp = (u < 4) ? finb : fin2b;
        const int oo = u & 3;
#pragma unroll
        for (int jj = 0; jj < 4; ++jj) fwp[jj] = Wp[oo * 4 + ((dr + jj) & 3)];
        fb = bp[oo];
    }

    // ---------------- x stream pointers; issue earliest loads first ----------
    const float4* dp = reinterpret_cast<const float4*>(dist) + (size_t)n * 2;
    constexpr size_t TS4 = (size_t)NB * 2;
    float4 x0a = dp[0],       x0b = dp[1];           // x(0) for the prologue
    float4 g0a = dp[TS4],     g0b = dp[TS4 + 1];     // ring: x1..x4
    float4 g1a = dp[2 * TS4], g1b = dp[2 * TS4 + 1];
    float4 g2a = dp[3 * TS4], g2b = dp[3 * TS4 + 1];
    float4 g3a = dp[4 * TS4], g3b = dp[4 * TS4 + 1];
    const float4* pf = dp + 5 * TS4;                  // next load: x5

    // ---------------- encoders (R6-verbatim; overlaps the loads above) -------
    v2f hp0, hp1, hp2, hp3;      // h0 generation (slot layout), read by L0 & L1
    v2f h10, h11, h12, h13;      // h1 state (slot layout)
    float c0, c1;
    {
        float s[16];
#pragma unroll
        for (int k = 0; k < 16; ++k) s[k] = state[n * 16 + k];
        float hm1[4], hm2[4];
#pragma unroll
        for (int m = 0; m < 4; ++m) {
            float a = e1b1[m], b = e2b1[m];
#pragma unroll
            for (int k = 0; k < 16; ++k) {
                a = fmaf(s[k], e1W1[m * 16 + k], a);
                b = fmaf(s[k], e2W1[m * 16 + k], b);
            }
            hm1[m] = fmaxf(a, 0.0f); hm2[m] = fmaxf(b, 0.0f);
        }
        float h0s[8], h1s[8];
#pragma unroll
        for (int k = 0; k < 8; ++k) {
            const int p = pidx(k);
            float a = e1b2[p], b = e1b2[8 + p];
#pragma unroll
            for (int m = 0; m < 4; ++m) {
                a = fmaf(hm1[m], e1W2[p * 4 + m], a);
                b = fmaf(hm1[m], e1W2[(8 + p) * 4 + m], b);
            }
            h0s[k] = fmaxf(a, 0.0f);
            h1s[k] = fmaxf(b, 0.0f);
        }
        float a = e2b2[u], b = e2b2[8 + u];
#pragma unroll
        for (int m = 0; m < 4; ++m) {
            a = fmaf(hm2[m], e2W2[u * 4 + m], a);
            b = fmaf(hm2[m], e2W2[(8 + u) * 4 + m], b);
        }
        c0 = fmaxf(a, 0.0f);
        c1 = fmaxf(b, 0.0f);
        hp0 = mkv2(h0s[0], h0s[1]); hp1 = mkv2(h0s[2], h0s[3]);
        hp2 = mkv2(h0s[4], h0s[5]); hp3 = mkv2(h0s[6], h0s[7]);
        h10 = mkv2(h1s[0], h1s[1]); h11 = mkv2(h1s[2], h1s[3]);
        h12 = mkv2(h1s[4], h1s[5]); h13 = mkv2(h1s[6], h1s[7]);
    }

    float* outp = out + ((u < 4) ? ((size_t)n * 4 + u)
                                 : ((size_t)T_STEPS * NB * 4 + (size_t)n * 4 + (u - 4)));
    const bool doStore = (q < 8);
    const v2f zero2 = mkv2(0.0f, 0.0f);

    // L0(t): consumes x(t) + hp (= h0(t-1)); produces hc (h0(t)). Chain A.
    v2f hc0, hc1, hc2, hc3;
    auto L0body = [&](const float4& lo, const float4& hi) {
        const v2f X0 = mkv2(lo.x, lo.y), X1 = mkv2(lo.z, lo.w);
        const v2f X2 = mkv2(hi.x, hi.y), X3 = mkv2(hi.z, hi.w);
        v2f pa = pkfma(X0, wx0a[0], mkv2(bA0, 0.0f));
        pa = pkfma(X1, wx0a[1], pa);
        pa = pkfma(hp0, wh0a[0], pa);
        pa = pkfma(hp1, wh0a[1], pa);
        v2f qa = pkfma(X2, wx0a[2], zero2);
        qa = pkfma(X3, wx0a[3], qa);
        qa = pkfma(hp2, wh0a[2], qa);
        qa = pkfma(hp3, wh0a[3], qa);
        v2f sa = pa + qa;
        const float A = sa.x + sa.y;
        v2f pb = pkfma(X0, wx0b[0], mkv2(bB0, 0.0f));
        pb = pkfma(X1, wx0b[1], pb);
        pb = pkfma(hp0, wh0b[0], pb);
        pb = pkfma(hp1, wh0b[1], pb);
        v2f qb = pkfma(X2, wx0b[2], zero2);
        qb = pkfma(X3, wx0b[3], qb);
        qb = pkfma(hp2, wh0b[2], qb);
        qb = pkfma(hp3, wh0b[3], qb);
        v2f sb = pb + qb;
        const float B = sb.x + sb.y;
        float a0 = fmaf(frcp(1.0f + fexp2(A)), mulA, addA);  // sig(i)|tanh(g)
        float a1 = frcp(1.0f + fexp2(B));                     // sig(f)|sig(o)
        const float s0 = dppf<0x128>(a0);
        const float s1 = dppf<0x128>(a1);
        const float prod = a0 * s0;
        const float fg = hlf ? s1 : a1;
        const float og = hlf ? a1 : s1;
        c0 = fmaf(fg, c0, prod);
        const float rr  = frcp(1.0f + fexp2(c0 * (-2.0f * LOG2E)));
        const float og2 = og + og;                            // off the serial chain
        const float hn  = fmaf(og2, rr, -og);                 // og * tanh(c0)
        const float t1 = dppf<0x121>(hn), t2 = dppf<0x122>(hn), t3 = dppf<0x123>(hn);
        const float t4 = dppf<0x124>(hn), t5 = dppf<0x125>(hn), t6 = dppf<0x126>(hn);
        const float t7 = dppf<0x127>(hn);
        hc0 = mkv2(hn, t1); hc1 = mkv2(t2, t3);
        hc2 = mkv2(t4, t5); hc3 = mkv2(t6, t7);
    };

    // L1(t-1)+dec+store: consumes hp (= h0(t-1)) + h1 state; independent of L0.
    auto L1decBody = [&](float* op) {
        v2f pa = pkfma(hp0, wx1a[0], mkv2(bA1, 0.0f));
        pa = pkfma(hp1, wx1a[1], pa);
        pa = pkfma(h10, wh1a[0], pa);
        pa = pkfma(h11, wh1a[1], pa);
        v2f qa = pkfma(hp2, wx1a[2], zero2);
        qa = pkfma(hp3, wx1a[3], qa);
        qa = pkfma(h12, wh1a[2], qa);
        qa = pkfma(h13, wh1a[3], qa);
        v2f sa = pa + qa;
        const float A = sa.x + sa.y;
        v2f pb = pkfma(hp0, wx1b[0], mkv2(bB1, 0.0f));
        pb = pkfma(hp1, wx1b[1], pb);
        pb = pkfma(h10, wh1b[0], pb);
        pb = pkfma(h11, wh1b[1], pb);
        v2f qb = pkfma(hp2, wx1b[2], zero2);
        qb = pkfma(hp3, wx1b[3], qb);
        qb = pkfma(h12, wh1b[2], qb);
        qb = pkfma(h13, wh1b[3], qb);
        v2f sb = pb + qb;
        const float B = sb.x + sb.y;
        float a0 = fmaf(frcp(1.0f + fexp2(A)), mulA, addA);
        float a1 = frcp(1.0f + fexp2(B));
        const float s0 = dppf<0x128>(a0);
        const float s1 = dppf<0x128>(a1);
        const float prod = a0 * s0;
        const float fg = hlf ? s1 : a1;
        const float og = hlf ? a1 : s1;
        c1 = fmaf(fg, c1, prod);
        const float rr  = frcp(1.0f + fexp2(c1 * (-2.0f * LOG2E)));
        const float og2 = og + og;
        const float hn  = fmaf(og2, rr, -og);
        const float t1 = dppf<0x121>(hn), t2 = dppf<0x122>(hn), t3 = dppf<0x123>(hn);
        const float t4 = dppf<0x124>(hn), t5 = dppf<0x125>(hn), t6 = dppf<0x126>(hn);
        const float t7 = dppf<0x127>(hn);
        h10 = mkv2(hn, t1); h11 = mkv2(t2, t3);
        h12 = mkv2(t4, t5); h13 = mkv2(t6, t7);
        // decoder + heads on fresh h1
        v2f dd = pkfma(h10, dwr2[0], mkv2(db, 0.0f));
        dd = pkfma(h11, dwr2[1], dd);
        v2f de = pkfma(h12, dwr2[2], zero2);
        de = pkfma(h13, dwr2[3], de);
        v2f ds = dd + de;
        float da = fmaxf(ds.x + ds.y, 0.0f);
        const float d1 = dppf<0x39>(da);
        const float d2 = dppf<0x4E>(da);
        const float d3 = dppf<0x93>(da);
        float o = fb;
        o = fmaf(da, fwp[0], o); o = fmaf(d1, fwp[1], o);
        o = fmaf(d2, fwp[2], o); o = fmaf(d3, fwp[3], o);
        if (doStore) *op = o;
    };

    // ---------------- prologue: L0(0) alone ----------------
    L0body(x0a, x0b);
    hp0 = hc0; hp1 = hc1; hp2 = hc2; hp3 = hc3;

    // ---------------- main loop: bodies consume x1..x996 ----------------
    for (int it = 0; it < 249; ++it) {
        float4 na, nb;
        na = pf[0]; nb = pf[1]; pf += TS4;
        L0body(g0a, g0b); L1decBody(outp); outp += (size_t)NB * 4;
        hp0 = hc0; hp1 = hc1; hp2 = hc2; hp3 = hc3;
        g0a = na; g0b = nb;
        na = pf[0]; nb = pf[1]; pf += TS4;
        L0body(g1a, g1b); L1decBody(outp); outp += (size_t)NB * 4;
        hp0 = hc0; hp1 = hc1; hp2 = hc2; hp3 = hc3;
        g1a = na; g1b = nb;
        na = pf[0]; nb = pf[1]; pf += TS4;
        L0body(g2a, g2b); L1decBody(outp); outp += (size_t)NB * 4;
        hp0 = hc0; hp1 = hc1; hp2 = hc2; hp3 = hc3;
        g2a = na; g2b = nb;
        const float4* pfx = (it == 248) ? dp : pf;   // clamp the x(1000) load
        na = pfx[0]; nb = pfx[1]; pf += TS4;
        L0body(g3a, g3b); L1decBody(outp); outp += (size_t)NB * 4;
        hp0 = hc0; hp1 = hc1; hp2 = hc2; hp3 = hc3;
        g3a = na; g3b = nb;
    }
    // ---------------- tail: x997..x999 (in ring; no loads) ----------------
    L0body(g0a, g0b); L1decBody(outp); outp += (size_t)NB * 4;
    hp0 = hc0; hp1 = hc1; hp2 = hc2; hp3 = hc3;
    L0body(g1a, g1b); L1decBody(outp); outp += (size_t)NB * 4;
    hp0 = hc0; hp1 = hc1; hp2 = hc2; hp3 = hc3;
    L0body(g2a, g2b); L1decBody(outp); outp += (size_t)NB * 4;
    hp0 = hc0; hp1 = hc1; hp2 = hc2; hp3 = hc3;
    // ---------------- epilogue: L1(999)+dec+store ----------------
    L1decBody(outp);
}

} // namespace

extern "C" void kernel_launch(void* const* d_in, const int* in_sizes, int n_in,
                              void* d_out, int out_size, void* d_ws, size_t ws_size,
                              hipStream_t stream) {
    const float* state = (const float*)d_in[0];
    const float* dist  = (const float*)d_in[1];
    const float* e1W1  = (const float*)d_in[2];
    const float* e1b1  = (const float*)d_in[3];
    const float* e1W2  = (const float*)d_in[4];
    const float* e1b2  = (const float*)d_in[5];
    const float* e2W1  = (const float*)d_in[6];
    const float* e2b1  = (const float*)d_in[7];
    const float* e2W2  = (const float*)d_in[8];
    const float* e2b2  = (const float*)d_in[9];
    const float* Wih0  = (const float*)d_in[10];
    const float* Whh0  = (const float*)d_in[11];
    const float* bih0  = (const float*)d_in[12];
    const float* bhh0  = (const float*)d_in[13];
    const float* Wih1  = (const float*)d_in[14];
    const float* Whh1  = (const float*)d_in[15];
    const float* bih1  = (const float*)d_in[16];
    const float* bhh1  = (const float*)d_in[17];
    const float* decW  = (const float*)d_in[18];
    const float* decb  = (const float*)d_in[19];
    const float* finW  = (const float*)d_in[20];
    const float* finb  = (const float*)d_in[21];
    const float* fin2W = (const float*)d_in[22];
    const float* fin2b = (const float*)d_in[23];
    float* outp = (float*)d_out;

    lstm_fused_kernel<<<dim3(NB / 16), dim3(256), 0, stream>>>(
        state, dist,
        e1W1, e1b1, e1W2, e1b2,
        e2W1, e2b1, e2W2, e2b2,
        Wih0, Whh0, bih0, bhh0,
        Wih1, Whh1, bih1, bhh1,
        decW, decb, finW, finb, fin2W, fin2b,
        outp);
}

// Round 9
// 294.568 us; speedup vs baseline: 1.5613x; 1.0450x over previous
//
#include <hip/hip_runtime.h>

namespace {

constexpr int T_STEPS = 1000;
constexpr int NB      = 4096;
constexpr float LOG2E = 1.4426950408889634f;

typedef float v2f __attribute__((ext_vector_type(2)));

__device__ __forceinline__ float fexp2(float x) { return __builtin_amdgcn_exp2f(x); }
__device__ __forceinline__ float frcp(float x)  { return __builtin_amdgcn_rcpf(x); }
__device__ __forceinline__ v2f mkv2(float a, float b) { v2f r; r.x = a; r.y = b; return r; }

__device__ __forceinline__ v2f pkfma(v2f a, v2f b, v2f c) {
#if __has_builtin(__builtin_elementwise_fma)
    return __builtin_elementwise_fma(a, b, c);   // v_pk_fma_f32
#else
    v2f r; r.x = fmaf(a.x, b.x, c.x); r.y = fmaf(a.y, b.y, c.y); return r;
#endif
}

// DPP on the VALU pipe (R3/R6-HW-proven patterns).
template<int CTRL>
__device__ __forceinline__ float dppf(float v) {
    int i = __float_as_int(v);
    return __int_as_float(__builtin_amdgcn_update_dpp(i, i, CTRL, 0xF, 0xF, false));
}

// W=16 (R6 mapping) + in-lane L0/L1 pipelining (R8) + TRUE distance-8
// x-prefetch: 8 named slots, sub-step t consumes slot (t&7) then reloads the
// SAME slot with x(t+8) -- no rotation copies, so the first use of each load
// is ~8 sub-steps (~1700 cy) after issue and HBM latency is fully hidden.
// h0 state ping-pongs between hE/hO by compile-time sub-step parity (no
// hp=hc copies). 1 wave/SIMD is structural, so VGPR spend is free.
__global__ __launch_bounds__(256, 1)
void lstm_fused_kernel(
    const float* __restrict__ state, const float* __restrict__ dist,
    const float* __restrict__ e1W1, const float* __restrict__ e1b1,
    const float* __restrict__ e1W2, const float* __restrict__ e1b2,
    const float* __restrict__ e2W1, const float* __restrict__ e2b1,
    const float* __restrict__ e2W2, const float* __restrict__ e2b2,
    const float* __restrict__ Wih0, const float* __restrict__ Whh0,
    const float* __restrict__ bih0, const float* __restrict__ bhh0,
    const float* __restrict__ Wih1, const float* __restrict__ Whh1,
    const float* __restrict__ bih1, const float* __restrict__ bhh1,
    const float* __restrict__ decW, const float* __restrict__ decb,
    const float* __restrict__ finW, const float* __restrict__ finb,
    const float* __restrict__ fin2W, const float* __restrict__ fin2b,
    float* __restrict__ out)
{
    const int tid = (int)threadIdx.x;
    const int q   = tid & 15;
    const int n   = blockIdx.x * 16 + (tid >> 4);
    const int u   = q & 7;
    const int hlf = q >> 3;
    const int r0  = hlf * 16 + u;   // row A (i_u | g_u)
    const int r1  = r0 + 8;         // row B (f_u | o_u)

    // probe row_ror direction once: slot k holds h[(u+sgn*k)&7]
    const int pv  = __builtin_amdgcn_update_dpp(0, q, 0x121, 0xF, 0xF, true);
    const int sgn = (pv == ((q + 1) & 15)) ? 1 : -1;
    auto pidx = [&](int k) { return (u + sgn * k) & 7; };

    const float sA   = hlf ? (-2.0f * LOG2E) : (-LOG2E);   // row A: sigmoid | tanh
    const float sB   = -LOG2E;                              // row B always sigmoid
    const float mulA = hlf ? 2.0f : 1.0f;
    const float addA = hlf ? -1.0f : 0.0f;

    // ---- packed weight rows (R6-verbatim; h-side in rotated slot layout) ----
    v2f wx0a[4], wh0a[4], wx0b[4], wh0b[4];
    v2f wx1a[4], wh1a[4], wx1b[4], wh1b[4];
#pragma unroll
    for (int k = 0; k < 4; ++k) {
        const int k0 = 2 * k, k1 = 2 * k + 1;
        const int p0 = pidx(k0), p1 = pidx(k1);
        wx0a[k] = mkv2(Wih0[r0 * 8 + k0] * sA, Wih0[r0 * 8 + k1] * sA);
        wh0a[k] = mkv2(Whh0[r0 * 8 + p0] * sA, Whh0[r0 * 8 + p1] * sA);
        wx0b[k] = mkv2(Wih0[r1 * 8 + k0] * sB, Wih0[r1 * 8 + k1] * sB);
        wh0b[k] = mkv2(Whh0[r1 * 8 + p0] * sB, Whh0[r1 * 8 + p1] * sB);
        wx1a[k] = mkv2(Wih1[r0 * 8 + p0] * sA, Wih1[r0 * 8 + p1] * sA);
        wh1a[k] = mkv2(Whh1[r0 * 8 + p0] * sA, Whh1[r0 * 8 + p1] * sA);
        wx1b[k] = mkv2(Wih1[r1 * 8 + p0] * sB, Wih1[r1 * 8 + p1] * sB);
        wh1b[k] = mkv2(Whh1[r1 * 8 + p0] * sB, Whh1[r1 * 8 + p1] * sB);
    }
    const v2f vbA0 = mkv2((bih0[r0] + bhh0[r0]) * sA, 0.0f);
    const v2f vbB0 = mkv2((bih0[r1] + bhh0[r1]) * sB, 0.0f);
    const v2f vbA1 = mkv2((bih1[r0] + bhh1[r0]) * sA, 0.0f);
    const v2f vbB1 = mkv2((bih1[r1] + bhh1[r1]) * sB, 0.0f);

    // decoder (R6-verbatim)
    const int dr = q & 3;
    v2f dwr2[4];
#pragma unroll
    for (int k = 0; k < 4; ++k)
        dwr2[k] = mkv2(decW[dr * 8 + pidx(2 * k)], decW[dr * 8 + pidx(2 * k + 1)]);
    const v2f vdb = mkv2(decb[dr], 0.0f);
    float fwp[4]; float fb;
    {
        const float* Wp = (u < 4) ? finW : fin2W;
        const float* bp = (u < 4) ? finb : fin2b;
        const int oo = u & 3;
#pragma unroll
        for (int jj = 0; jj < 4; ++jj) fwp[jj] = Wp[oo * 4 + ((dr + jj) & 3)];
        fb = bp[oo];
    }

    // ---------------- x slots: issue x(0..7) loads first ----------------
    const float4* dp = reinterpret_cast<const float4*>(dist) + (size_t)n * 2;
    constexpr size_t TS4 = (size_t)NB * 2;
    float4 x0a = dp[0 * TS4], x0b = dp[0 * TS4 + 1];
    float4 x1a = dp[1 * TS4], x1b = dp[1 * TS4 + 1];
    float4 x2a = dp[2 * TS4], x2b = dp[2 * TS4 + 1];
    float4 x3a = dp[3 * TS4], x3b = dp[3 * TS4 + 1];
    float4 x4a = dp[4 * TS4], x4b = dp[4 * TS4 + 1];
    float4 x5a = dp[5 * TS4], x5b = dp[5 * TS4 + 1];
    float4 x6a = dp[6 * TS4], x6b = dp[6 * TS4 + 1];
    float4 x7a = dp[7 * TS4], x7b = dp[7 * TS4 + 1];

    // ---------------- encoders (R6-verbatim; overlaps loads) ----------------
    v2f hE0, hE1, hE2, hE3;       // h0 at even t
    v2f hO0, hO1, hO2, hO3;       // h0 at odd t (init = h0(-1))
    v2f h10, h11, h12, h13;       // h1 state
    float c0, c1;
    {
        float s[16];
#pragma unroll
        for (int k = 0; k < 16; ++k) s[k] = state[n * 16 + k];
        float hm1[4], hm2[4];
#pragma unroll
        for (int m = 0; m < 4; ++m) {
            float a = e1b1[m], b = e2b1[m];
#pragma unroll
            for (int k = 0; k < 16; ++k) {
                a = fmaf(s[k], e1W1[m * 16 + k], a);
                b = fmaf(s[k], e2W1[m * 16 + k], b);
            }
            hm1[m] = fmaxf(a, 0.0f); hm2[m] = fmaxf(b, 0.0f);
        }
        float h0s[8], h1s[8];
#pragma unroll
        for (int k = 0; k < 8; ++k) {
            const int p = pidx(k);
            float a = e1b2[p], b = e1b2[8 + p];
#pragma unroll
            for (int m = 0; m < 4; ++m) {
                a = fmaf(hm1[m], e1W2[p * 4 + m], a);
                b = fmaf(hm1[m], e1W2[(8 + p) * 4 + m], b);
            }
            h0s[k] = fmaxf(a, 0.0f);
            h1s[k] = fmaxf(b, 0.0f);
        }
        float a = e2b2[u], b = e2b2[8 + u];
#pragma unroll
        for (int m = 0; m < 4; ++m) {
            a = fmaf(hm2[m], e2W2[u * 4 + m], a);
            b = fmaf(hm2[m], e2W2[(8 + u) * 4 + m], b);
        }
        c0 = fmaxf(a, 0.0f);
        c1 = fmaxf(b, 0.0f);
        hO0 = mkv2(h0s[0], h0s[1]); hO1 = mkv2(h0s[2], h0s[3]);
        hO2 = mkv2(h0s[4], h0s[5]); hO3 = mkv2(h0s[6], h0s[7]);
        hE0 = hO0; hE1 = hO1; hE2 = hO2; hE3 = hO3;
        h10 = mkv2(h1s[0], h1s[1]); h11 = mkv2(h1s[2], h1s[3]);
        h12 = mkv2(h1s[4], h1s[5]); h13 = mkv2(h1s[6], h1s[7]);
    }

    float* outp = out + ((u < 4) ? ((size_t)n * 4 + u)
                                 : ((size_t)T_STEPS * NB * 4 + (size_t)n * 4 + (u - 4)));
    const bool doStore = (q < 8);
    const v2f zero2 = mkv2(0.0f, 0.0f);

    // L0(t): x(t) + h0(t-1) [read regs] -> h0(t) [write regs]. One chain.
    auto L0body = [&](const float4& lo, const float4& hi,
                      const v2f& R0, const v2f& R1, const v2f& R2, const v2f& R3,
                      v2f& W0, v2f& W1, v2f& W2, v2f& W3) {
        const v2f X0 = mkv2(lo.x, lo.y), X1 = mkv2(lo.z, lo.w);
        const v2f X2 = mkv2(hi.x, hi.y), X3 = mkv2(hi.z, hi.w);
        v2f pa = pkfma(X0, wx0a[0], vbA0);
        pa = pkfma(X1, wx0a[1], pa);
        pa = pkfma(R0, wh0a[0], pa);
        pa = pkfma(R1, wh0a[1], pa);
        v2f qa = pkfma(X2, wx0a[2], zero2);
        qa = pkfma(X3, wx0a[3], qa);
        qa = pkfma(R2, wh0a[2], qa);
        qa = pkfma(R3, wh0a[3], qa);
        v2f sa = pa + qa;
        const float A = sa.x + sa.y;
        v2f pb = pkfma(X0, wx0b[0], vbB0);
        pb = pkfma(X1, wx0b[1], pb);
        pb = pkfma(R0, wh0b[0], pb);
        pb = pkfma(R1, wh0b[1], pb);
        v2f qb = pkfma(X2, wx0b[2], zero2);
        qb = pkfma(X3, wx0b[3], qb);
        qb = pkfma(R2, wh0b[2], qb);
        qb = pkfma(R3, wh0b[3], qb);
        v2f sb = pb + qb;
        const float B = sb.x + sb.y;
        float a0 = fmaf(frcp(1.0f + fexp2(A)), mulA, addA);  // sig(i)|tanh(g)
        float a1 = frcp(1.0f + fexp2(B));                     // sig(f)|sig(o)
        const float s0 = dppf<0x128>(a0);
        const float s1 = dppf<0x128>(a1);
        const float prod = a0 * s0;
        const float fg = hlf ? s1 : a1;
        const float og = hlf ? a1 : s1;
        c0 = fmaf(fg, c0, prod);
        const float rr  = frcp(1.0f + fexp2(c0 * (-2.0f * LOG2E)));
        const float og2 = og + og;
        const float hn  = fmaf(og2, rr, -og);                 // og * tanh(c0)
        const float t1 = dppf<0x121>(hn), t2 = dppf<0x122>(hn), t3 = dppf<0x123>(hn);
        const float t4 = dppf<0x124>(hn), t5 = dppf<0x125>(hn), t6 = dppf<0x126>(hn);
        const float t7 = dppf<0x127>(hn);
        W0 = mkv2(hn, t1); W1 = mkv2(t2, t3);
        W2 = mkv2(t4, t5); W3 = mkv2(t6, t7);
    };

    // L1(t-1)+dec+store: consumes h0(t-1) [same read regs] + h1 state in place.
    auto L1decBody = [&](const v2f& R0, const v2f& R1, const v2f& R2, const v2f& R3,
                         float* op) {
        v2f pa = pkfma(R0, wx1a[0], vbA1);
        pa = pkfma(R1, wx1a[1], pa);
        pa = pkfma(h10, wh1a[0], pa);
        pa = pkfma(h11, wh1a[1], pa);
        v2f qa = pkfma(R2, wx1a[2], zero2);
        qa = pkfma(R3, wx1a[3], qa);
        qa = pkfma(h12, wh1a[2], qa);
        qa = pkfma(h13, wh1a[3], qa);
        v2f sa = pa + qa;
        const float A = sa.x + sa.y;
        v2f pb = pkfma(R0, wx1b[0], vbB1);
        pb = pkfma(R1, wx1b[1], pb);
        pb = pkfma(h10, wh1b[0], pb);
        pb = pkfma(h11, wh1b[1], pb);
        v2f qb = pkfma(R2, wx1b[2], zero2);
        qb = pkfma(R3, wx1b[3], qb);
        qb = pkfma(h12, wh1b[2], qb);
        qb = pkfma(h13, wh1b[3], qb);
        v2f sb = pb + qb;
        const float B = sb.x + sb.y;
        float a0 = fmaf(frcp(1.0f + fexp2(A)), mulA, addA);
        float a1 = frcp(1.0f + fexp2(B));
        const float s0 = dppf<0x128>(a0);
        const float s1 = dppf<0x128>(a1);
        const float prod = a0 * s0;
        const float fg = hlf ? s1 : a1;
        const float og = hlf ? a1 : s1;
        c1 = fmaf(fg, c1, prod);
        const float rr  = frcp(1.0f + fexp2(c1 * (-2.0f * LOG2E)));
        const float og2 = og + og;
        const float hn  = fmaf(og2, rr, -og);
        const float t1 = dppf<0x121>(hn), t2 = dppf<0x122>(hn), t3 = dppf<0x123>(hn);
        const float t4 = dppf<0x124>(hn), t5 = dppf<0x125>(hn), t6 = dppf<0x126>(hn);
        const float t7 = dppf<0x127>(hn);
        h10 = mkv2(hn, t1); h11 = mkv2(t2, t3);
        h12 = mkv2(t4, t5); h13 = mkv2(t6, t7);
        // decoder + heads on fresh h1
        v2f dd = pkfma(h10, dwr2[0], vdb);
        dd = pkfma(h11, dwr2[1], dd);
        v2f de = pkfma(h12, dwr2[2], zero2);
        de = pkfma(h13, dwr2[3], de);
        v2f ds = dd + de;
        float da = fmaxf(ds.x + ds.y, 0.0f);
        const float d1 = dppf<0x39>(da);
        const float d2 = dppf<0x4E>(da);
        const float d3 = dppf<0x93>(da);
        float o = fb;
        o = fmaf(da, fwp[0], o); o = fmaf(d1, fwp[1], o);
        o = fmaf(d2, fwp[2], o); o = fmaf(d3, fwp[3], o);
        if (doStore) *op = o;
    };

    // consume slot, reload SAME slot with x(t+8), then L1(t-1)+dec+store.
#define SUBSTEP(XA, XB, R0, R1, R2, R3, W0, W1, W2, W3, LP)               \
    L0body(XA, XB, R0, R1, R2, R3, W0, W1, W2, W3);                       \
    XA = (LP)[0]; XB = (LP)[1];                                           \
    L1decBody(R0, R1, R2, R3, outp); outp += (size_t)NB * 4;

#define SUBTAIL(XA, XB, R0, R1, R2, R3, W0, W1, W2, W3)                   \
    L0body(XA, XB, R0, R1, R2, R3, W0, W1, W2, W3);                       \
    L1decBody(R0, R1, R2, R3, outp); outp += (size_t)NB * 4;

    // prologue: t=0 (even): L0 only; slot0 reloads x8.
    L0body(x0a, x0b, hO0, hO1, hO2, hO3, hE0, hE1, hE2, hE3);
    x0a = dp[8 * TS4]; x0b = dp[8 * TS4 + 1];

    // main: k=0..123, sub-step i handles t=8k+1+i (slot (1+i)&7), loads x(t+8).
    const float4* pf = dp + 9 * TS4;
    for (int k = 0; k < 124; ++k) {
        const float4* pb = pf;
        const float4* p7 = (k == 123) ? dp : (pb + 7 * TS4);  // clamp x(1000)
        SUBSTEP(x1a, x1b, hE0, hE1, hE2, hE3, hO0, hO1, hO2, hO3, pb + 0 * TS4)  // t odd
        SUBSTEP(x2a, x2b, hO0, hO1, hO2, hO3, hE0, hE1, hE2, hE3, pb + 1 * TS4)  // t even
        SUBSTEP(x3a, x3b, hE0, hE1, hE2, hE3, hO0, hO1, hO2, hO3, pb + 2 * TS4)
        SUBSTEP(x4a, x4b, hO0, hO1, hO2, hO3, hE0, hE1, hE2, hE3, pb + 3 * TS4)
        SUBSTEP(x5a, x5b, hE0, hE1, hE2, hE3, hO0, hO1, hO2, hO3, pb + 4 * TS4)
        SUBSTEP(x6a, x6b, hO0, hO1, hO2, hO3, hE0, hE1, hE2, hE3, pb + 5 * TS4)
        SUBSTEP(x7a, x7b, hE0, hE1, hE2, hE3, hO0, hO1, hO2, hO3, pb + 6 * TS4)
        SUBSTEP(x0a, x0b, hO0, hO1, hO2, hO3, hE0, hE1, hE2, hE3, p7)            // t=8k+8
        pf += 8 * TS4;
    }
    // tail: t=993..999 (slots 1..7 already loaded; no more loads)
    SUBTAIL(x1a, x1b, hE0, hE1, hE2, hE3, hO0, hO1, hO2, hO3)   // 993
    SUBTAIL(x2a, x2b, hO0, hO1, hO2, hO3, hE0, hE1, hE2, hE3)   // 994
    SUBTAIL(x3a, x3b, hE0, hE1, hE2, hE3, hO0, hO1, hO2, hO3)   // 995
    SUBTAIL(x4a, x4b, hO0, hO1, hO2, hO3, hE0, hE1, hE2, hE3)   // 996
    SUBTAIL(x5a, x5b, hE0, hE1, hE2, hE3, hO0, hO1, hO2, hO3)   // 997
    SUBTAIL(x6a, x6b, hO0, hO1, hO2, hO3, hE0, hE1, hE2, hE3)   // 998
    SUBTAIL(x7a, x7b, hE0, hE1, hE2, hE3, hO0, hO1, hO2, hO3)   // 999
    // epilogue: L1(999)+dec+store (h0(999) sits in hO)
    L1decBody(hO0, hO1, hO2, hO3, outp);

#undef SUBSTEP
#undef SUBTAIL
}

} // namespace

extern "C" void kernel_launch(void* const* d_in, const int* in_sizes, int n_in,
                              void* d_out, int out_size, void* d_ws, size_t ws_size,
                              hipStream_t stream) {
    const float* state = (const float*)d_in[0];
    const float* dist  = (const float*)d_in[1];
    const float* e1W1  = (const float*)d_in[2];
    const float* e1b1  = (const float*)d_in[3];
    const float* e1W2  = (const float*)d_in[4];
    const float* e1b2  = (const float*)d_in[5];
    const float* e2W1  = (const float*)d_in[6];
    const float* e2b1  = (const float*)d_in[7];
    const float* e2W2  = (const float*)d_in[8];
    const float* e2b2  = (const float*)d_in[9];
    const float* Wih0  = (const float*)d_in[10];
    const float* Whh0  = (const float*)d_in[11];
    const float* bih0  = (const float*)d_in[12];
    const float* bhh0  = (const float*)d_in[13];
    const float* Wih1  = (const float*)d_in[14];
    const float* Whh1  = (const float*)d_in[15];
    const float* bih1  = (const float*)d_in[16];
    const float* bhh1  = (const float*)d_in[17];
    const float* decW  = (const float*)d_in[18];
    const float* decb  = (const float*)d_in[19];
    const float* finW  = (const float*)d_in[20];
    const float* finb  = (const float*)d_in[21];
    const float* fin2W = (const float*)d_in[22];
    const float* fin2b = (const float*)d_in[23];
    float* outp = (float*)d_out;

    lstm_fused_kernel<<<dim3(NB / 16), dim3(256), 0, stream>>>(
        state, dist,
        e1W1, e1b1, e1W2, e1b2,
        e2W1, e2b1, e2W2, e2b2,
        Wih0, Whh0, bih0, bhh0,
        Wih1, Whh1, bih1, bhh1,
        decW, decb, finW, finb, fin2W, fin2b,
        outp);
}